// Round 5
// baseline (616.337 us; speedup 1.0000x reference)
//
#include <hip/hip_runtime.h>
#include <hip/hip_bf16.h>
#include <math.h>

// ---------------------------------------------------------------------------
// GAT 3-layer forward.
//  - GEMMs: split-bf16 (bf16x3) on MFMA pipe; C written as fp16 feat table.
//    LDS staging via global_load_lds, XOR-swizzled (proven 0 conflicts),
//    DOUBLE-BUFFERED with counted s_waitcnt vmcnt(8) + raw s_barrier
//    (never drain vmcnt to 0 in the loop): tile kt+1's loads stay in flight
//    across the barriers and the MFMA phase. No __syncthreads in the K-loop.
//    SPLITA (L0): A fp32 loads issued at loop head (issue-early), cvt +
//    swizzled ds_write after the MFMA block (write-late).
//    elr (el/er attention dots) fused into the GEMM epilogue.
//  - agg: wave-per-node, SINGLE pass (deferred softmax normalization).
// ---------------------------------------------------------------------------

#define HID 256

typedef __attribute__((ext_vector_type(8))) __bf16 bf16x8;
typedef __attribute__((ext_vector_type(4))) __bf16 bf16x4;
typedef __attribute__((ext_vector_type(8))) _Float16 half8;
typedef __attribute__((ext_vector_type(4))) _Float16 half4;
typedef __attribute__((ext_vector_type(4))) float floatx4;

__device__ __forceinline__ void gl_lds16(const void* g, void* l) {
    __builtin_amdgcn_global_load_lds(
        (const __attribute__((address_space(1))) void*)g,
        (__attribute__((address_space(3))) void*)l, 16, 0, 0);
}

// ---------------- CSR build ----------------

__global__ void hist_kernel(const int* __restrict__ dst, int* __restrict__ cnt, int E) {
    int e = blockIdx.x * blockDim.x + threadIdx.x;
    if (e < E) atomicAdd(&cnt[dst[e]], 1);
}

__global__ __launch_bounds__(256) void scan1_kernel(const int* __restrict__ cnt,
                                                    int* __restrict__ bsum, int n) {
    __shared__ int w[4];
    int t = threadIdx.x;
    int i = blockIdx.x * 256 + t;
    int c = (i < n) ? cnt[i] : 0;
    int acc = c;
#pragma unroll
    for (int off = 32; off > 0; off >>= 1) acc += __shfl_xor(acc, off);
    if ((t & 63) == 0) w[t >> 6] = acc;
    __syncthreads();
    if (t == 0) bsum[blockIdx.x] = w[0] + w[1] + w[2] + w[3];
}

__global__ __launch_bounds__(256) void scan2_kernel(const int* __restrict__ bsum,
                                                    int* __restrict__ boff, int nb) {
    __shared__ int buf[256];
    int t = threadIdx.x;
    int v = (t < nb) ? bsum[t] : 0;
    buf[t] = v;
    __syncthreads();
    for (int off = 1; off < 256; off <<= 1) {
        int x = (t >= off) ? buf[t - off] : 0;
        __syncthreads();
        buf[t] += x;
        __syncthreads();
    }
    if (t < nb) boff[t] = buf[t] - v;
}

__global__ __launch_bounds__(256) void scan3_kernel(const int* __restrict__ cnt,
                                                    const int* __restrict__ boff,
                                                    int* __restrict__ rowptr,
                                                    int* __restrict__ cursor, int n) {
    __shared__ int buf[256];
    int t = threadIdx.x;
    int i = blockIdx.x * 256 + t;
    int c = (i < n) ? cnt[i] : 0;
    buf[t] = c;
    __syncthreads();
    for (int off = 1; off < 256; off <<= 1) {
        int x = (t >= off) ? buf[t - off] : 0;
        __syncthreads();
        buf[t] += x;
        __syncthreads();
    }
    int start = boff[blockIdx.x] + buf[t] - c;
    if (i < n) {
        rowptr[i] = start;
        cursor[i] = start;
        if (i == n - 1) rowptr[n] = start + c;
    }
}

__global__ void fill_kernel(const int* __restrict__ src, const int* __restrict__ dst,
                            int* __restrict__ cursor, int* __restrict__ adj, int E) {
    int e = blockIdx.x * blockDim.x + threadIdx.x;
    if (e < E) {
        int d = dst[e];
        int pos = atomicAdd(&cursor[d], 1);
        adj[pos] = src[e];
    }
}

// ---------------- all weight matrices -> transposed bf16 hi/lo --------------

__device__ __forceinline__ void splitT_one(const float* W, __bf16* ht, __bf16* lt,
                                           int idx, int K) {
    int k = idx >> 8, n = idx & 255;  // Nn == 256
    float v = W[idx];
    __bf16 h = (__bf16)v;
    ht[(size_t)n * K + k] = h;
    lt[(size_t)n * K + k] = (__bf16)(v - (float)h);
}

__global__ __launch_bounds__(256) void splitT_all_kernel(
    const float* __restrict__ W0, const float* __restrict__ W1,
    const float* __restrict__ W2, __bf16* h0, __bf16* l0, __bf16* h1,
    __bf16* l1, __bf16* h2, __bf16* l2) {
    int i = blockIdx.x * 256 + threadIdx.x;
    const int n0 = 512 * 256, n1 = 256 * 256;
    if (i < n0) splitT_one(W0, h0, l0, i, 512);
    else if (i < n0 + n1) splitT_one(W1, h1, l1, i - n0, 256);
    else if (i < n0 + 2 * n1) splitT_one(W2, h2, l2, i - n0 - n1, 256);
}

// ---------------- MFMA GEMM + fused elr ----------------
// C[M,256](fp16) = (Ah+Al)@(Bh+Bl);  el/er[row,h] = C_row . al/ar (fp32 acc).
// SPLITA: A is fp32, split to bf16 hi/lo in registers (write-late).
// LDS tile layout: [128 rows][4 slots x 16B]; lds_slot = gslot ^ ((row>>1)&3).
// Double-buffered; counted vmcnt(8) + raw s_barrier (no __syncthreads).

template <bool SPLITA>
__global__ __launch_bounds__(256, 2) void gemm_mfma_kernel(
    const float* __restrict__ Af, const __bf16* __restrict__ Ah,
    const __bf16* __restrict__ Al, const __bf16* __restrict__ Bht,
    const __bf16* __restrict__ Blt, _Float16* __restrict__ C,
    const float* __restrict__ al, const float* __restrict__ ar,
    float* __restrict__ el, float* __restrict__ er, int M, int K, int H) {
    __shared__ __bf16 sAh[2][4096];
    __shared__ __bf16 sAl[2][4096];
    __shared__ __bf16 sBh[2][4096];
    __shared__ __bf16 sBl[2][4096];

    int t = threadIdx.x;
    int wave = t >> 6, lane = t & 63;
    int wr = wave >> 1, wc = wave & 1;
    int quad = lane >> 4, m16 = lane & 15;

    int rowA0 = blockIdx.y * 128;
    int rowB0 = blockIdx.x * 128;

    // gl_lds staging coords: thread t -> LDS linear chunk t*16B
    // = (row t>>2, lds_slot t&3); load global slot (t&3)^((t>>3)&3).
    int sr = t >> 2;
    int ke = ((t & 3) ^ ((t >> 3) & 3)) * 8;  // swizzled global k-chunk (elems)
    int ldso = t * 8;
    // SPLITA reg-staging coords: thread t -> row t>>1, cols kb..kb+15
    int srow = t >> 1;
    int kb = (t & 1) * 16;
    int s0 = (t & 1) * 2;
    int ssw = (srow >> 1) & 3;
    int soA = srow * 32 + (s0 ^ ssw) * 8;        // slot for cols kb..kb+7
    int soB = srow * 32 + ((s0 + 1) ^ ssw) * 8;  // slot for cols kb+8..kb+15

    size_t ar0 = 0, ar1 = 0, af0 = 0;
    if (SPLITA) {
        af0 = (size_t)min(rowA0 + srow, M - 1) * K + kb;
    } else {
        ar0 = (size_t)min(rowA0 + sr, M - 1) * K;
        ar1 = (size_t)min(rowA0 + sr + 64, M - 1) * K;
    }
    size_t br0 = (size_t)(rowB0 + sr) * K;
    size_t br1 = (size_t)(rowB0 + sr + 64) * K;

    // per-lane swizzled fragment slot offset (elems): quad ^ ((m16>>1)&3)
    int qsw = (quad ^ ((m16 >> 1) & 3)) * 8;

    floatx4 acc[4][4];
    floatx4 z = {0.f, 0.f, 0.f, 0.f};
#pragma unroll
    for (int i = 0; i < 4; i++)
#pragma unroll
        for (int j = 0; j < 4; j++) acc[i][j] = z;

    int nk = K >> 5;

    // ---- prologue: stage tile 0 into buffer 0 ----
    float4 p0, p1, p2, p3;
    if (SPLITA) {
        const float* ap = Af + af0;
        p0 = ((const float4*)ap)[0];
        p1 = ((const float4*)ap)[1];
        p2 = ((const float4*)ap)[2];
        p3 = ((const float4*)ap)[3];
    }
    gl_lds16(Bht + br0 + ke, &sBh[0][ldso]);
    gl_lds16(Bht + br1 + ke, &sBh[0][2048 + ldso]);
    gl_lds16(Blt + br0 + ke, &sBl[0][ldso]);
    gl_lds16(Blt + br1 + ke, &sBl[0][2048 + ldso]);
    if (!SPLITA) {
        gl_lds16(Ah + ar0 + ke, &sAh[0][ldso]);
        gl_lds16(Ah + ar1 + ke, &sAh[0][2048 + ldso]);
        gl_lds16(Al + ar0 + ke, &sAl[0][ldso]);
        gl_lds16(Al + ar1 + ke, &sAl[0][2048 + ldso]);
    }
    if (SPLITA) {
        // cvt + swizzled ds_write of A tile 0 (compiler waits for p0..p3)
        float vv[16] = {p0.x, p0.y, p0.z, p0.w, p1.x, p1.y, p1.z, p1.w,
                        p2.x, p2.y, p2.z, p2.w, p3.x, p3.y, p3.z, p3.w};
        bf16x8 h0, h1, l0, l1;
#pragma unroll
        for (int c = 0; c < 8; c++) {
            __bf16 hv = (__bf16)vv[c];
            h0[c] = hv;
            l0[c] = (__bf16)(vv[c] - (float)hv);
            __bf16 hv2 = (__bf16)vv[8 + c];
            h1[c] = hv2;
            l1[c] = (__bf16)(vv[8 + c] - (float)hv2);
        }
        *(bf16x8*)&sAh[0][soA] = h0;
        *(bf16x8*)&sAh[0][soB] = h1;
        *(bf16x8*)&sAl[0][soA] = l0;
        *(bf16x8*)&sAl[0][soB] = l1;
    }

    int cur = 0;
    for (int kt = 0; kt < nk; kt++) {
        int nxt = cur ^ 1;
        bool have = (kt + 1 < nk);

        // ---- issue next tile's loads (A regs first, then B gl_lds) ----
        if (have) {
            int k1 = (kt + 1) << 5;
            if (SPLITA) {
                const float* ap = Af + af0 + k1;
                p0 = ((const float4*)ap)[0];
                p1 = ((const float4*)ap)[1];
                p2 = ((const float4*)ap)[2];
                p3 = ((const float4*)ap)[3];
            }
            int k0s = k1 + ke;
            gl_lds16(Bht + br0 + k0s, &sBh[nxt][ldso]);
            gl_lds16(Bht + br1 + k0s, &sBh[nxt][2048 + ldso]);
            gl_lds16(Blt + br0 + k0s, &sBl[nxt][ldso]);
            gl_lds16(Blt + br1 + k0s, &sBl[nxt][2048 + ldso]);
            if (!SPLITA) {
                gl_lds16(Ah + ar0 + k0s, &sAh[nxt][ldso]);
                gl_lds16(Ah + ar1 + k0s, &sAh[nxt][2048 + ldso]);
                gl_lds16(Al + ar0 + k0s, &sAl[nxt][ldso]);
                gl_lds16(Al + ar1 + k0s, &sAl[nxt][2048 + ldso]);
            }
            // retire tile kt's staging loads; keep kt+1's in flight
            asm volatile("s_waitcnt vmcnt(8)" ::: "memory");
        } else {
            asm volatile("s_waitcnt vmcnt(0)" ::: "memory");
        }
        asm volatile("s_waitcnt lgkmcnt(0)" ::: "memory");
        __builtin_amdgcn_s_barrier();

        // ---- fragment reads from buf cur (swizzled) + MFMA ----
        bf16x8 fah[4], fal[4], fbh[4], fbl[4];
#pragma unroll
        for (int i = 0; i < 4; i++) {
            int off = (wr * 64 + i * 16 + m16) * 32 + qsw;
            fah[i] = *(const bf16x8*)&sAh[cur][off];
            fal[i] = *(const bf16x8*)&sAl[cur][off];
        }
#pragma unroll
        for (int j = 0; j < 4; j++) {
            int off = (wc * 64 + j * 16 + m16) * 32 + qsw;
            fbh[j] = *(const bf16x8*)&sBh[cur][off];
            fbl[j] = *(const bf16x8*)&sBl[cur][off];
        }
#pragma unroll
        for (int i = 0; i < 4; i++)
#pragma unroll
            for (int j = 0; j < 4; j++) {
                acc[i][j] = __builtin_amdgcn_mfma_f32_16x16x32_bf16(fah[i], fbh[j], acc[i][j], 0, 0, 0);
                acc[i][j] = __builtin_amdgcn_mfma_f32_16x16x32_bf16(fah[i], fbl[j], acc[i][j], 0, 0, 0);
                acc[i][j] = __builtin_amdgcn_mfma_f32_16x16x32_bf16(fal[i], fbh[j], acc[i][j], 0, 0, 0);
            }

        // ---- SPLITA write-late: cvt + swizzled ds_write into buf nxt ----
        if (SPLITA && have) {
            float vv[16] = {p0.x, p0.y, p0.z, p0.w, p1.x, p1.y, p1.z, p1.w,
                            p2.x, p2.y, p2.z, p2.w, p3.x, p3.y, p3.z, p3.w};
            bf16x8 h0, h1, l0, l1;
#pragma unroll
            for (int c = 0; c < 8; c++) {
                __bf16 hv = (__bf16)vv[c];
                h0[c] = hv;
                l0[c] = (__bf16)(vv[c] - (float)hv);
                __bf16 hv2 = (__bf16)vv[8 + c];
                h1[c] = hv2;
                l1[c] = (__bf16)(vv[8 + c] - (float)hv2);
            }
            *(bf16x8*)&sAh[nxt][soA] = h0;
            *(bf16x8*)&sAh[nxt][soB] = h1;
            *(bf16x8*)&sAl[nxt][soA] = l0;
            *(bf16x8*)&sAl[nxt][soB] = l1;
        }
        asm volatile("s_waitcnt lgkmcnt(0)" ::: "memory");
        __builtin_amdgcn_s_barrier();
        cur = nxt;
    }

    // C store (C/D layout: col = m16, row = quad*4 + reg)
#pragma unroll
    for (int i = 0; i < 4; i++) {
        int rowb = rowA0 + wr * 64 + i * 16 + quad * 4;
#pragma unroll
        for (int j = 0; j < 4; j++) {
            int col = rowB0 + wc * 64 + j * 16 + m16;
#pragma unroll
            for (int r = 0; r < 4; r++) {
                int row = rowb + r;
                if (row < M) C[(size_t)row * HID + col] = (_Float16)acc[i][j][r];
            }
        }
    }

    // fused elr: per-row dot with al/ar over this wave's 64-col head chunk
    float alv[4], arv[4];
#pragma unroll
    for (int j = 0; j < 4; j++) {
        int col = rowB0 + wc * 64 + j * 16 + m16;
        alv[j] = al[col];
        arv[j] = ar[col];
    }
    int h = ((rowB0 + wc * 64) >> 6) & (H - 1);
#pragma unroll
    for (int i = 0; i < 4; i++) {
        int rowb = rowA0 + wr * 64 + i * 16 + quad * 4;
#pragma unroll
        for (int r = 0; r < 4; r++) {
            float pe = acc[i][0][r] * alv[0] + acc[i][1][r] * alv[1] +
                       acc[i][2][r] * alv[2] + acc[i][3][r] * alv[3];
            float pr = acc[i][0][r] * arv[0] + acc[i][1][r] * arv[1] +
                       acc[i][2][r] * arv[2] + acc[i][3][r] * arv[3];
#pragma unroll
            for (int off = 1; off < 16; off <<= 1) {
                pe += __shfl_xor(pe, off);
                pr += __shfl_xor(pr, off);
            }
            int row = rowb + r;
            if (m16 == 0 && row < M) {
                if (H == 4) {
                    el[row * 4 + h] = pe;
                    er[row * 4 + h] = pr;
                } else {
                    atomicAdd(&el[row], pe);
                    atomicAdd(&er[row], pr);
                }
            }
        }
    }
}

// ---------------- fp32 GEMM fallback (writes fp16 feat) ----------------

__global__ __launch_bounds__(256) void gemm_kernel(const float* __restrict__ A,
                                                   const float* __restrict__ B,
                                                   _Float16* __restrict__ C,
                                                   int M, int K, int Nn) {
    __shared__ float As[16][128];
    __shared__ float Bs[16][128];

    int t = threadIdx.x;
    int tx = t & 15, ty = t >> 4;
    int arow = t >> 1;
    int acol = (t & 1) * 8;
    int brow = t >> 4;
    int bcol = (t & 15) * 8;

    int gArow = blockIdx.y * 128 + arow;
    const float* aPtr = A + (size_t)gArow * K + acol;
    const float* bPtr = B + (size_t)brow * Nn + blockIdx.x * 128 + bcol;

    float acc[8][8];
#pragma unroll
    for (int i = 0; i < 8; i++)
#pragma unroll
        for (int j = 0; j < 8; j++) acc[i][j] = 0.f;

    bool aok = (gArow < M);
    int nk = K >> 4;
    for (int kt = 0; kt < nk; kt++) {
        int k0 = kt << 4;
        float4 av0 = make_float4(0.f, 0.f, 0.f, 0.f), av1 = av0;
        if (aok) {
            av0 = *(const float4*)(aPtr + k0);
            av1 = *(const float4*)(aPtr + k0 + 4);
        }
        float4 bv0 = *(const float4*)(bPtr + (size_t)k0 * Nn);
        float4 bv1 = *(const float4*)(bPtr + (size_t)k0 * Nn + 4);

        As[acol + 0][arow] = av0.x;
        As[acol + 1][arow] = av0.y;
        As[acol + 2][arow] = av0.z;
        As[acol + 3][arow] = av0.w;
        As[acol + 4][arow] = av1.x;
        As[acol + 5][arow] = av1.y;
        As[acol + 6][arow] = av1.z;
        As[acol + 7][arow] = av1.w;
        *(float4*)&Bs[brow][bcol] = bv0;
        *(float4*)&Bs[brow][bcol + 4] = bv1;
        __syncthreads();

#pragma unroll
        for (int kk = 0; kk < 16; kk++) {
            float4 a0 = *(const float4*)&As[kk][ty * 4];
            float4 a1 = *(const float4*)&As[kk][64 + ty * 4];
            float4 b0 = *(const float4*)&Bs[kk][tx * 4];
            float4 b1 = *(const float4*)&Bs[kk][64 + tx * 4];
            float a[8] = {a0.x, a0.y, a0.z, a0.w, a1.x, a1.y, a1.z, a1.w};
            float b[8] = {b0.x, b0.y, b0.z, b0.w, b1.x, b1.y, b1.z, b1.w};
#pragma unroll
            for (int i = 0; i < 8; i++)
#pragma unroll
                for (int j = 0; j < 8; j++) acc[i][j] = fmaf(a[i], b[j], acc[i][j]);
        }
        __syncthreads();
    }

    int c0 = blockIdx.x * 128 + tx * 4;
#pragma unroll
    for (int half = 0; half < 2; half++) {
#pragma unroll
        for (int i = 0; i < 4; i++) {
            int r = blockIdx.y * 128 + half * 64 + ty * 4 + i;
            if (r < M) {
                _Float16* cp = C + (size_t)r * Nn + c0;
                int ai = half * 4 + i;
#pragma unroll
                for (int j = 0; j < 4; j++) {
                    cp[j] = (_Float16)acc[ai][j];
                    cp[64 + j] = (_Float16)acc[ai][4 + j];
                }
            }
        }
    }
}

// ---------------- el/er (fallback path only) ----------------

__global__ __launch_bounds__(256) void elr_kernel(const _Float16* __restrict__ feat,
                                                  const float* __restrict__ al,
                                                  const float* __restrict__ ar,
                                                  float* __restrict__ el,
                                                  float* __restrict__ er, int H) {
    int n = blockIdx.x, t = threadIdx.x;
    float f = (float)feat[(size_t)n * HID + t];
    float a = f * al[t];
    float b = f * ar[t];
#pragma unroll
    for (int off = 32; off > 0; off >>= 1) {
        a += __shfl_xor(a, off);
        b += __shfl_xor(b, off);
    }
    __shared__ float pa[4], pb[4];
    int wave = t >> 6, lane = t & 63;
    if (lane == 0) { pa[wave] = a; pb[wave] = b; }
    __syncthreads();
    if (H == 4) {
        if (t < 4) {
            el[n * 4 + t] = pa[t];
            er[n * 4 + t] = pb[t];
        }
    } else {
        if (t == 0) {
            el[n] = pa[0] + pa[1] + pa[2] + pa[3];
            er[n] = pb[0] + pb[1] + pb[2] + pb[3];
        }
    }
}

// ---------------- agg: wave-per-node, SINGLE pass, deferred softmax norm ----
// msg = (sum_e ex_e * feat[u_e]) / (sum_e ex_e), ex = exp(lrelu(el[u]+er[v])).
// Both sums accumulated in one sweep over the adjacency; divide at the end.

template <int H, bool RELU, bool WF32, bool WSPLIT>
__global__ __launch_bounds__(256) void agg_tpl(
    const _Float16* __restrict__ feat, const float* __restrict__ el,
    const float* __restrict__ er, const int* __restrict__ rowptr,
    const int* __restrict__ adj, const float* __restrict__ bias,
    float* __restrict__ outf, __bf16* __restrict__ oh, __bf16* __restrict__ ol,
    int N) {
    int wave = threadIdx.x >> 6, lane = threadIdx.x & 63;
    int v = blockIdx.x * 4 + wave;
    if (v >= N) return;
    int row0 = rowptr[v];
    int deg = rowptr[v + 1] - row0;

    int l32 = lane & 31;
    int half = lane >> 5;
    int hd = (H == 4) ? (l32 >> 3) : 0;
    int d0 = l32 * 8;

    float o[8];
    if (deg > 0) {
        float er_h = (H == 4) ? er[v * 4 + hd] : er[v];
        const int* adjr = adj + row0;

        float a[8];
#pragma unroll
        for (int j = 0; j < 8; j++) a[j] = 0.f;
        float sl = 0.f;

        int e = 0;
        // 16 edges per iteration (8 per half-wave)
        for (; e + 16 <= deg; e += 16) {
            int u[8];
            half8 f[8];
            float elv[8];
#pragma unroll
            for (int q = 0; q < 8; q++) u[q] = adjr[e + q * 2 + half];
#pragma unroll
            for (int q = 0; q < 8; q++)
                f[q] = *(const half8*)&feat[(size_t)u[q] * HID + d0];
#pragma unroll
            for (int q = 0; q < 8; q++)
                elv[q] = (H == 4) ? el[u[q] * 4 + hd] : el[u[q]];
#pragma unroll
            for (int q = 0; q < 8; q++) {
                float sc = elv[q] + er_h;
                sc = (sc > 0.f) ? sc : 0.2f * sc;
                float ex = __expf(sc);
                sl += ex;
#pragma unroll
                for (int j = 0; j < 8; j++) a[j] = fmaf(ex, (float)f[q][j], a[j]);
            }
        }
        // 8 edges per iteration
        for (; e + 8 <= deg; e += 8) {
            int u[4];
            half8 f[4];
            float elv[4];
#pragma unroll
            for (int q = 0; q < 4; q++) u[q] = adjr[e + q * 2 + half];
#pragma unroll
            for (int q = 0; q < 4; q++)
                f[q] = *(const half8*)&feat[(size_t)u[q] * HID + d0];
#pragma unroll
            for (int q = 0; q < 4; q++)
                elv[q] = (H == 4) ? el[u[q] * 4 + hd] : el[u[q]];
#pragma unroll
            for (int q = 0; q < 4; q++) {
                float sc = elv[q] + er_h;
                sc = (sc > 0.f) ? sc : 0.2f * sc;
                float ex = __expf(sc);
                sl += ex;
#pragma unroll
                for (int j = 0; j < 8; j++) a[j] = fmaf(ex, (float)f[q][j], a[j]);
            }
        }
        // tail: 2 edges, predicated
        for (; e < deg; e += 2) {
            int ee = e + half;
            bool act = ee < deg;
            int es = act ? ee : (deg - 1);
            int u = adjr[es];
            float elvq = (H == 4) ? el[u * 4 + hd] : el[u];
            half8 f = *(const half8*)&feat[(size_t)u * HID + d0];
            float sc = elvq + er_h;
            sc = (sc > 0.f) ? sc : 0.2f * sc;
            float ex = act ? __expf(sc) : 0.f;
            sl += ex;
#pragma unroll
            for (int j = 0; j < 8; j++) a[j] = fmaf(ex, (float)f[j], a[j]);
        }

        // merge halves (each half holds partial msg + partial ex-sum)
#pragma unroll
        for (int j = 0; j < 8; j++) a[j] += __shfl_xor(a[j], 32);
        sl += __shfl_xor(sl, 32);
        float inv = 1.f / sl;

#pragma unroll
        for (int j = 0; j < 8; j++) {
            o[j] = fmaf(a[j], inv, bias[d0 + j]);
            if (RELU) o[j] = fmaxf(o[j], 0.f);
        }
    } else {
#pragma unroll
        for (int j = 0; j < 8; j++) {
            o[j] = bias[d0 + j];
            if (RELU) o[j] = fmaxf(o[j], 0.f);
        }
    }

    if (half == 0) {
        size_t base = (size_t)v * HID + d0;
        if (WF32) {
            *(float4*)&outf[base] = make_float4(o[0], o[1], o[2], o[3]);
            *(float4*)&outf[base + 4] = make_float4(o[4], o[5], o[6], o[7]);
        }
        if (WSPLIT) {
            bf16x8 hh, ll;
#pragma unroll
            for (int j = 0; j < 8; j++) {
                __bf16 hv = (__bf16)o[j];
                hh[j] = hv;
                ll[j] = (__bf16)(o[j] - (float)hv);
            }
            *(bf16x8*)&oh[base] = hh;
            *(bf16x8*)&ol[base] = ll;
        }
    }
}

// ---------------- launch ----------------

extern "C" void kernel_launch(void* const* d_in, const int* in_sizes, int n_in,
                              void* d_out, int out_size, void* d_ws, size_t ws_size,
                              hipStream_t stream) {
    const float* feats = (const float*)d_in[0];
    const int* src = (const int*)d_in[1];
    const int* dst = (const int*)d_in[2];
    const float* W0 = (const float*)d_in[3];
    const float* al0 = (const float*)d_in[4];
    const float* ar0 = (const float*)d_in[5];
    const float* b0 = (const float*)d_in[6];
    const float* W1 = (const float*)d_in[7];
    const float* al1 = (const float*)d_in[8];
    const float* ar1 = (const float*)d_in[9];
    const float* b1 = (const float*)d_in[10];
    const float* W2 = (const float*)d_in[11];
    const float* al2 = (const float*)d_in[12];
    const float* ar2 = (const float*)d_in[13];
    const float* b2 = (const float*)d_in[14];
    float* out = (float*)d_out;

    const int IN_DIM = 512;
    const int N = in_sizes[0] / IN_DIM;   // 50000
    const int E = in_sizes[1];            // 800000

    char* ws = (char*)d_ws;
    size_t off = 0;
    auto alloc = [&](size_t bytes) -> void* {
        void* p = ws + off;
        off = (off + bytes + 255) & ~(size_t)255;
        return p;
    };
    _Float16* featbuf = (_Float16*)alloc((size_t)N * HID * sizeof(_Float16));  // 25.6 MB
    float* el = (float*)alloc((size_t)N * 4 * sizeof(float));
    float* er = (float*)alloc((size_t)N * 4 * sizeof(float));
    int* cnt = (int*)alloc((size_t)N * sizeof(int));
    int* rowptr = (int*)alloc((size_t)(N + 1) * sizeof(int));
    int* cursor = (int*)alloc((size_t)N * sizeof(int));
    int* adj = (int*)alloc((size_t)E * sizeof(int));
    int nscanb = (N + 255) / 256;
    int* bsum = (int*)alloc((size_t)nscanb * sizeof(int));
    int* boff = (int*)alloc((size_t)nscanb * sizeof(int));
    __bf16* Ah = (__bf16*)alloc((size_t)N * HID * sizeof(__bf16));             // 25.6 MB
    __bf16* Al = (__bf16*)alloc((size_t)N * HID * sizeof(__bf16));             // 25.6 MB
    __bf16* Bht0 = (__bf16*)alloc((size_t)512 * HID * sizeof(__bf16));
    __bf16* Blt0 = (__bf16*)alloc((size_t)512 * HID * sizeof(__bf16));
    __bf16* Bht1 = (__bf16*)alloc((size_t)256 * HID * sizeof(__bf16));
    __bf16* Blt1 = (__bf16*)alloc((size_t)256 * HID * sizeof(__bf16));
    __bf16* Bht2 = (__bf16*)alloc((size_t)256 * HID * sizeof(__bf16));
    __bf16* Blt2 = (__bf16*)alloc((size_t)256 * HID * sizeof(__bf16));
    bool use_mfma = (off <= ws_size);

    // CSR build
    hipMemsetAsync(cnt, 0, (size_t)N * sizeof(int), stream);
    hist_kernel<<<(E + 255) / 256, 256, 0, stream>>>(dst, cnt, E);
    scan1_kernel<<<nscanb, 256, 0, stream>>>(cnt, bsum, N);
    scan2_kernel<<<1, 256, 0, stream>>>(bsum, boff, nscanb);
    scan3_kernel<<<nscanb, 256, 0, stream>>>(cnt, boff, rowptr, cursor, N);
    fill_kernel<<<(E + 255) / 256, 256, 0, stream>>>(src, dst, cursor, adj, E);

    dim3 ggrid(HID / 128, (N + 127) / 128);
    int aggb = (N + 3) / 4;

    if (use_mfma) {
        // all weights -> transposed bf16 hi/lo, one kernel
        splitT_all_kernel<<<(512 * 256 + 2 * 256 * 256) / 256, 256, 0, stream>>>(
            W0, W1, W2, Bht0, Blt0, Bht1, Blt1, Bht2, Blt2);

        // layer 0: 512 -> 4x64, relu (A split fused into staging; elr fused)
        gemm_mfma_kernel<true><<<ggrid, 256, 0, stream>>>(
            feats, nullptr, nullptr, Bht0, Blt0, featbuf, al0, ar0, el, er, N, 512, 4);
        agg_tpl<4, true, false, true><<<aggb, 256, 0, stream>>>(
            featbuf, el, er, rowptr, adj, b0, nullptr, Ah, Al, N);

        // layer 1: 256 -> 4x64, relu
        gemm_mfma_kernel<false><<<ggrid, 256, 0, stream>>>(
            nullptr, Ah, Al, Bht1, Blt1, featbuf, al1, ar1, el, er, N, 256, 4);
        agg_tpl<4, true, false, true><<<aggb, 256, 0, stream>>>(
            featbuf, el, er, rowptr, adj, b1, nullptr, Ah, Al, N);

        // layer 2: 256 -> 1x256, no act (elr via atomics -> zero first)
        hipMemsetAsync(el, 0, (size_t)N * 8 * sizeof(float), stream);  // el+er contiguous
        gemm_mfma_kernel<false><<<ggrid, 256, 0, stream>>>(
            nullptr, Ah, Al, Bht2, Blt2, featbuf, al2, ar2, el, er, N, 256, 1);
        agg_tpl<1, false, true, false><<<aggb, 256, 0, stream>>>(
            featbuf, el, er, rowptr, adj, b2, out, nullptr, nullptr, N);
    } else {
        gemm_kernel<<<ggrid, 256, 0, stream>>>(feats, W0, featbuf, N, 512, HID);
        elr_kernel<<<N, 256, 0, stream>>>(featbuf, al0, ar0, el, er, 4);
        agg_tpl<4, true, true, false><<<aggb, 256, 0, stream>>>(
            featbuf, el, er, rowptr, adj, b0, out, nullptr, nullptr, N);

        gemm_kernel<<<ggrid, 256, 0, stream>>>(out, W1, featbuf, N, 256, HID);
        elr_kernel<<<N, 256, 0, stream>>>(featbuf, al1, ar1, el, er, 4);
        agg_tpl<4, true, true, false><<<aggb, 256, 0, stream>>>(
            featbuf, el, er, rowptr, adj, b1, out, nullptr, nullptr, N);

        gemm_kernel<<<ggrid, 256, 0, stream>>>(out, W2, featbuf, N, 256, HID);
        elr_kernel<<<N, 256, 0, stream>>>(featbuf, al2, ar2, el, er, 1);
        agg_tpl<1, false, true, false><<<aggb, 256, 0, stream>>>(
            featbuf, el, er, rowptr, adj, b2, out, nullptr, nullptr, N);
    }
}

// Round 6
// 605.278 us; speedup vs baseline: 1.0183x; 1.0183x over previous
//
#include <hip/hip_runtime.h>
#include <hip/hip_bf16.h>
#include <math.h>

// ---------------------------------------------------------------------------
// GAT 3-layer forward.
//  - GEMMs: split-bf16 (bf16x3) on MFMA pipe; C written as fp16 feat table.
//    BM=64 x BN=128 tiles -> grid 1564 blocks (~6/CU) to fix grid-bound
//    occupancy (was 782 blocks, ~3/CU, 22% occ). Single-buffered LDS staging
//    via global_load_lds + XOR swizzle (proven 0 conflicts), two barriers
//    per K-step (R4 schedule, best measured). LDS 24 KB/block.
//    L0 fuses fp32->bf16 hi/lo split into staging (SPLITA).
//    elr (el/er attention dots) fused into the GEMM epilogue.
//  - agg: wave-per-node, SINGLE pass (deferred softmax normalization).
// ---------------------------------------------------------------------------

#define HID 256

typedef __attribute__((ext_vector_type(8))) __bf16 bf16x8;
typedef __attribute__((ext_vector_type(4))) __bf16 bf16x4;
typedef __attribute__((ext_vector_type(8))) _Float16 half8;
typedef __attribute__((ext_vector_type(4))) _Float16 half4;
typedef __attribute__((ext_vector_type(4))) float floatx4;

__device__ __forceinline__ void gl_lds16(const void* g, void* l) {
    __builtin_amdgcn_global_load_lds(
        (const __attribute__((address_space(1))) void*)g,
        (__attribute__((address_space(3))) void*)l, 16, 0, 0);
}

// ---------------- CSR build ----------------

__global__ void hist_kernel(const int* __restrict__ dst, int* __restrict__ cnt, int E) {
    int e = blockIdx.x * blockDim.x + threadIdx.x;
    if (e < E) atomicAdd(&cnt[dst[e]], 1);
}

__global__ __launch_bounds__(256) void scan1_kernel(const int* __restrict__ cnt,
                                                    int* __restrict__ bsum, int n) {
    __shared__ int w[4];
    int t = threadIdx.x;
    int i = blockIdx.x * 256 + t;
    int c = (i < n) ? cnt[i] : 0;
    int acc = c;
#pragma unroll
    for (int off = 32; off > 0; off >>= 1) acc += __shfl_xor(acc, off);
    if ((t & 63) == 0) w[t >> 6] = acc;
    __syncthreads();
    if (t == 0) bsum[blockIdx.x] = w[0] + w[1] + w[2] + w[3];
}

__global__ __launch_bounds__(256) void scan2_kernel(const int* __restrict__ bsum,
                                                    int* __restrict__ boff, int nb) {
    __shared__ int buf[256];
    int t = threadIdx.x;
    int v = (t < nb) ? bsum[t] : 0;
    buf[t] = v;
    __syncthreads();
    for (int off = 1; off < 256; off <<= 1) {
        int x = (t >= off) ? buf[t - off] : 0;
        __syncthreads();
        buf[t] += x;
        __syncthreads();
    }
    if (t < nb) boff[t] = buf[t] - v;
}

__global__ __launch_bounds__(256) void scan3_kernel(const int* __restrict__ cnt,
                                                    const int* __restrict__ boff,
                                                    int* __restrict__ rowptr,
                                                    int* __restrict__ cursor, int n) {
    __shared__ int buf[256];
    int t = threadIdx.x;
    int i = blockIdx.x * 256 + t;
    int c = (i < n) ? cnt[i] : 0;
    buf[t] = c;
    __syncthreads();
    for (int off = 1; off < 256; off <<= 1) {
        int x = (t >= off) ? buf[t - off] : 0;
        __syncthreads();
        buf[t] += x;
        __syncthreads();
    }
    int start = boff[blockIdx.x] + buf[t] - c;
    if (i < n) {
        rowptr[i] = start;
        cursor[i] = start;
        if (i == n - 1) rowptr[n] = start + c;
    }
}

__global__ void fill_kernel(const int* __restrict__ src, const int* __restrict__ dst,
                            int* __restrict__ cursor, int* __restrict__ adj, int E) {
    int e = blockIdx.x * blockDim.x + threadIdx.x;
    if (e < E) {
        int d = dst[e];
        int pos = atomicAdd(&cursor[d], 1);
        adj[pos] = src[e];
    }
}

// ---------------- all weight matrices -> transposed bf16 hi/lo --------------

__device__ __forceinline__ void splitT_one(const float* W, __bf16* ht, __bf16* lt,
                                           int idx, int K) {
    int k = idx >> 8, n = idx & 255;  // Nn == 256
    float v = W[idx];
    __bf16 h = (__bf16)v;
    ht[(size_t)n * K + k] = h;
    lt[(size_t)n * K + k] = (__bf16)(v - (float)h);
}

__global__ __launch_bounds__(256) void splitT_all_kernel(
    const float* __restrict__ W0, const float* __restrict__ W1,
    const float* __restrict__ W2, __bf16* h0, __bf16* l0, __bf16* h1,
    __bf16* l1, __bf16* h2, __bf16* l2) {
    int i = blockIdx.x * 256 + threadIdx.x;
    const int n0 = 512 * 256, n1 = 256 * 256;
    if (i < n0) splitT_one(W0, h0, l0, i, 512);
    else if (i < n0 + n1) splitT_one(W1, h1, l1, i - n0, 256);
    else if (i < n0 + 2 * n1) splitT_one(W2, h2, l2, i - n0 - n1, 256);
}

// ---------------- MFMA GEMM + fused elr ----------------
// C[M,256](fp16) = (Ah+Al)@(Bh+Bl);  el/er[row,h] = C_row . al/ar (fp32 acc).
// BM=64, BN=128; 4 waves (2x2), wave output 32x64, acc[2][4].
// LDS tile layout: [rows][4 slots x 16B]; lds_slot = gslot ^ ((row>>1)&3).
// SPLITA: A is fp32, split to bf16 hi/lo in registers during staging.

template <bool SPLITA>
__global__ __launch_bounds__(256, 4) void gemm_mfma_kernel(
    const float* __restrict__ Af, const __bf16* __restrict__ Ah,
    const __bf16* __restrict__ Al, const __bf16* __restrict__ Bht,
    const __bf16* __restrict__ Blt, _Float16* __restrict__ C,
    const float* __restrict__ al, const float* __restrict__ ar,
    float* __restrict__ el, float* __restrict__ er, int M, int K, int H) {
    __shared__ __bf16 sAh[64 * 32];    // 4 KB
    __shared__ __bf16 sAl[64 * 32];    // 4 KB
    __shared__ __bf16 sBh[128 * 32];   // 8 KB
    __shared__ __bf16 sBl[128 * 32];   // 8 KB

    int t = threadIdx.x;
    int wave = t >> 6, lane = t & 63;
    int wr = wave >> 1, wc = wave & 1;
    int quad = lane >> 4, m16 = lane & 15;

    int rowA0 = blockIdx.y * 64;
    int rowB0 = blockIdx.x * 128;

    // staging coords: thread t -> row t>>2, slot t&3 (16B chunks)
    int sr = t >> 2;
    int ke = ((t & 3) ^ ((t >> 3) & 3)) * 8;  // swizzled global k-chunk (elems)
    int ldso = t * 8;                          // linear LDS dest (elems)
    // SPLITA: natural global cols, swizzled ds_write dest
    int kb = (t & 3) * 8;
    int soA = sr * 32 + (((t & 3) ^ ((t >> 3) & 3)) * 8);

    size_t ar0 = 0, af0 = 0;
    if (SPLITA) {
        af0 = (size_t)min(rowA0 + sr, M - 1) * K + kb;
    } else {
        ar0 = (size_t)min(rowA0 + sr, M - 1) * K;
    }
    size_t br0 = (size_t)(rowB0 + sr) * K;
    size_t br1 = (size_t)(rowB0 + sr + 64) * K;

    // per-lane swizzled fragment slot offset (elems): quad ^ ((m16>>1)&3)
    int qsw = (quad ^ ((m16 >> 1) & 3)) * 8;

    floatx4 acc[2][4];
    floatx4 z = {0.f, 0.f, 0.f, 0.f};
#pragma unroll
    for (int i = 0; i < 2; i++)
#pragma unroll
        for (int j = 0; j < 4; j++) acc[i][j] = z;

    int nk = K >> 5;
    for (int kt = 0; kt < nk; kt++) {
        int k0 = kt << 5;
        int k0s = k0 + ke;
        gl_lds16(Bht + br0 + k0s, &sBh[ldso]);
        gl_lds16(Bht + br1 + k0s, &sBh[2048 + ldso]);
        gl_lds16(Blt + br0 + k0s, &sBl[ldso]);
        gl_lds16(Blt + br1 + k0s, &sBl[2048 + ldso]);
        if (SPLITA) {
            const float* ap = Af + af0 + k0;
            float4 v0 = ((const float4*)ap)[0];
            float4 v1 = ((const float4*)ap)[1];
            float vv[8] = {v0.x, v0.y, v0.z, v0.w, v1.x, v1.y, v1.z, v1.w};
            bf16x8 h0, l0;
#pragma unroll
            for (int c = 0; c < 8; c++) {
                __bf16 hv = (__bf16)vv[c];
                h0[c] = hv;
                l0[c] = (__bf16)(vv[c] - (float)hv);
            }
            *(bf16x8*)&sAh[soA] = h0;
            *(bf16x8*)&sAl[soA] = l0;
        } else {
            gl_lds16(Ah + ar0 + k0s, &sAh[ldso]);
            gl_lds16(Al + ar0 + k0s, &sAl[ldso]);
        }
        __syncthreads();

        bf16x8 fah[2], fal[2], fbh[4], fbl[4];
#pragma unroll
        for (int i = 0; i < 2; i++) {
            int off = (wr * 32 + i * 16 + m16) * 32 + qsw;
            fah[i] = *(const bf16x8*)&sAh[off];
            fal[i] = *(const bf16x8*)&sAl[off];
        }
#pragma unroll
        for (int j = 0; j < 4; j++) {
            int off = (wc * 64 + j * 16 + m16) * 32 + qsw;
            fbh[j] = *(const bf16x8*)&sBh[off];
            fbl[j] = *(const bf16x8*)&sBl[off];
        }
#pragma unroll
        for (int i = 0; i < 2; i++)
#pragma unroll
            for (int j = 0; j < 4; j++) {
                acc[i][j] = __builtin_amdgcn_mfma_f32_16x16x32_bf16(fah[i], fbh[j], acc[i][j], 0, 0, 0);
                acc[i][j] = __builtin_amdgcn_mfma_f32_16x16x32_bf16(fah[i], fbl[j], acc[i][j], 0, 0, 0);
                acc[i][j] = __builtin_amdgcn_mfma_f32_16x16x32_bf16(fal[i], fbh[j], acc[i][j], 0, 0, 0);
            }
        __syncthreads();
    }

    // C store (C/D layout: col = m16, row = quad*4 + reg)
#pragma unroll
    for (int i = 0; i < 2; i++) {
        int rowb = rowA0 + wr * 32 + i * 16 + quad * 4;
#pragma unroll
        for (int j = 0; j < 4; j++) {
            int col = rowB0 + wc * 64 + j * 16 + m16;
#pragma unroll
            for (int r = 0; r < 4; r++) {
                int row = rowb + r;
                if (row < M) C[(size_t)row * HID + col] = (_Float16)acc[i][j][r];
            }
        }
    }

    // fused elr: per-row dot with al/ar over this wave's 64-col head chunk
    float alv[4], arv[4];
#pragma unroll
    for (int j = 0; j < 4; j++) {
        int col = rowB0 + wc * 64 + j * 16 + m16;
        alv[j] = al[col];
        arv[j] = ar[col];
    }
    int h = ((rowB0 + wc * 64) >> 6) & (H - 1);
#pragma unroll
    for (int i = 0; i < 2; i++) {
        int rowb = rowA0 + wr * 32 + i * 16 + quad * 4;
#pragma unroll
        for (int r = 0; r < 4; r++) {
            float pe = acc[i][0][r] * alv[0] + acc[i][1][r] * alv[1] +
                       acc[i][2][r] * alv[2] + acc[i][3][r] * alv[3];
            float pr = acc[i][0][r] * arv[0] + acc[i][1][r] * arv[1] +
                       acc[i][2][r] * arv[2] + acc[i][3][r] * arv[3];
#pragma unroll
            for (int off = 1; off < 16; off <<= 1) {
                pe += __shfl_xor(pe, off);
                pr += __shfl_xor(pr, off);
            }
            int row = rowb + r;
            if (m16 == 0 && row < M) {
                if (H == 4) {
                    el[row * 4 + h] = pe;
                    er[row * 4 + h] = pr;
                } else {
                    atomicAdd(&el[row], pe);
                    atomicAdd(&er[row], pr);
                }
            }
        }
    }
}

// ---------------- fp32 GEMM fallback (writes fp16 feat) ----------------

__global__ __launch_bounds__(256) void gemm_kernel(const float* __restrict__ A,
                                                   const float* __restrict__ B,
                                                   _Float16* __restrict__ C,
                                                   int M, int K, int Nn) {
    __shared__ float As[16][128];
    __shared__ float Bs[16][128];

    int t = threadIdx.x;
    int tx = t & 15, ty = t >> 4;
    int arow = t >> 1;
    int acol = (t & 1) * 8;
    int brow = t >> 4;
    int bcol = (t & 15) * 8;

    int gArow = blockIdx.y * 128 + arow;
    const float* aPtr = A + (size_t)gArow * K + acol;
    const float* bPtr = B + (size_t)brow * Nn + blockIdx.x * 128 + bcol;

    float acc[8][8];
#pragma unroll
    for (int i = 0; i < 8; i++)
#pragma unroll
        for (int j = 0; j < 8; j++) acc[i][j] = 0.f;

    bool aok = (gArow < M);
    int nk = K >> 4;
    for (int kt = 0; kt < nk; kt++) {
        int k0 = kt << 4;
        float4 av0 = make_float4(0.f, 0.f, 0.f, 0.f), av1 = av0;
        if (aok) {
            av0 = *(const float4*)(aPtr + k0);
            av1 = *(const float4*)(aPtr + k0 + 4);
        }
        float4 bv0 = *(const float4*)(bPtr + (size_t)k0 * Nn);
        float4 bv1 = *(const float4*)(bPtr + (size_t)k0 * Nn + 4);

        As[acol + 0][arow] = av0.x;
        As[acol + 1][arow] = av0.y;
        As[acol + 2][arow] = av0.z;
        As[acol + 3][arow] = av0.w;
        As[acol + 4][arow] = av1.x;
        As[acol + 5][arow] = av1.y;
        As[acol + 6][arow] = av1.z;
        As[acol + 7][arow] = av1.w;
        *(float4*)&Bs[brow][bcol] = bv0;
        *(float4*)&Bs[brow][bcol + 4] = bv1;
        __syncthreads();

#pragma unroll
        for (int kk = 0; kk < 16; kk++) {
            float4 a0 = *(const float4*)&As[kk][ty * 4];
            float4 a1 = *(const float4*)&As[kk][64 + ty * 4];
            float4 b0 = *(const float4*)&Bs[kk][tx * 4];
            float4 b1 = *(const float4*)&Bs[kk][64 + tx * 4];
            float a[8] = {a0.x, a0.y, a0.z, a0.w, a1.x, a1.y, a1.z, a1.w};
            float b[8] = {b0.x, b0.y, b0.z, b0.w, b1.x, b1.y, b1.z, b1.w};
#pragma unroll
            for (int i = 0; i < 8; i++)
#pragma unroll
                for (int j = 0; j < 8; j++) acc[i][j] = fmaf(a[i], b[j], acc[i][j]);
        }
        __syncthreads();
    }

    int c0 = blockIdx.x * 128 + tx * 4;
#pragma unroll
    for (int half = 0; half < 2; half++) {
#pragma unroll
        for (int i = 0; i < 4; i++) {
            int r = blockIdx.y * 128 + half * 64 + ty * 4 + i;
            if (r < M) {
                _Float16* cp = C + (size_t)r * Nn + c0;
                int ai = half * 4 + i;
#pragma unroll
                for (int j = 0; j < 4; j++) {
                    cp[j] = (_Float16)acc[ai][j];
                    cp[64 + j] = (_Float16)acc[ai][4 + j];
                }
            }
        }
    }
}

// ---------------- el/er (fallback path only) ----------------

__global__ __launch_bounds__(256) void elr_kernel(const _Float16* __restrict__ feat,
                                                  const float* __restrict__ al,
                                                  const float* __restrict__ ar,
                                                  float* __restrict__ el,
                                                  float* __restrict__ er, int H) {
    int n = blockIdx.x, t = threadIdx.x;
    float f = (float)feat[(size_t)n * HID + t];
    float a = f * al[t];
    float b = f * ar[t];
#pragma unroll
    for (int off = 32; off > 0; off >>= 1) {
        a += __shfl_xor(a, off);
        b += __shfl_xor(b, off);
    }
    __shared__ float pa[4], pb[4];
    int wave = t >> 6, lane = t & 63;
    if (lane == 0) { pa[wave] = a; pb[wave] = b; }
    __syncthreads();
    if (H == 4) {
        if (t < 4) {
            el[n * 4 + t] = pa[t];
            er[n * 4 + t] = pb[t];
        }
    } else {
        if (t == 0) {
            el[n] = pa[0] + pa[1] + pa[2] + pa[3];
            er[n] = pb[0] + pb[1] + pb[2] + pb[3];
        }
    }
}

// ---------------- agg: wave-per-node, SINGLE pass, deferred softmax norm ----
// msg = (sum_e ex_e * feat[u_e]) / (sum_e ex_e), ex = exp(lrelu(el[u]+er[v])).
// Both sums accumulated in one sweep over the adjacency; divide at the end.

template <int H, bool RELU, bool WF32, bool WSPLIT>
__global__ __launch_bounds__(256) void agg_tpl(
    const _Float16* __restrict__ feat, const float* __restrict__ el,
    const float* __restrict__ er, const int* __restrict__ rowptr,
    const int* __restrict__ adj, const float* __restrict__ bias,
    float* __restrict__ outf, __bf16* __restrict__ oh, __bf16* __restrict__ ol,
    int N) {
    int wave = threadIdx.x >> 6, lane = threadIdx.x & 63;
    int v = blockIdx.x * 4 + wave;
    if (v >= N) return;
    int row0 = rowptr[v];
    int deg = rowptr[v + 1] - row0;

    int l32 = lane & 31;
    int half = lane >> 5;
    int hd = (H == 4) ? (l32 >> 3) : 0;
    int d0 = l32 * 8;

    float o[8];
    if (deg > 0) {
        float er_h = (H == 4) ? er[v * 4 + hd] : er[v];
        const int* adjr = adj + row0;

        float a[8];
#pragma unroll
        for (int j = 0; j < 8; j++) a[j] = 0.f;
        float sl = 0.f;

        int e = 0;
        // 16 edges per iteration (8 per half-wave)
        for (; e + 16 <= deg; e += 16) {
            int u[8];
            half8 f[8];
            float elv[8];
#pragma unroll
            for (int q = 0; q < 8; q++) u[q] = adjr[e + q * 2 + half];
#pragma unroll
            for (int q = 0; q < 8; q++)
                f[q] = *(const half8*)&feat[(size_t)u[q] * HID + d0];
#pragma unroll
            for (int q = 0; q < 8; q++)
                elv[q] = (H == 4) ? el[u[q] * 4 + hd] : el[u[q]];
#pragma unroll
            for (int q = 0; q < 8; q++) {
                float sc = elv[q] + er_h;
                sc = (sc > 0.f) ? sc : 0.2f * sc;
                float ex = __expf(sc);
                sl += ex;
#pragma unroll
                for (int j = 0; j < 8; j++) a[j] = fmaf(ex, (float)f[q][j], a[j]);
            }
        }
        // 8 edges per iteration
        for (; e + 8 <= deg; e += 8) {
            int u[4];
            half8 f[4];
            float elv[4];
#pragma unroll
            for (int q = 0; q < 4; q++) u[q] = adjr[e + q * 2 + half];
#pragma unroll
            for (int q = 0; q < 4; q++)
                f[q] = *(const half8*)&feat[(size_t)u[q] * HID + d0];
#pragma unroll
            for (int q = 0; q < 4; q++)
                elv[q] = (H == 4) ? el[u[q] * 4 + hd] : el[u[q]];
#pragma unroll
            for (int q = 0; q < 4; q++) {
                float sc = elv[q] + er_h;
                sc = (sc > 0.f) ? sc : 0.2f * sc;
                float ex = __expf(sc);
                sl += ex;
#pragma unroll
                for (int j = 0; j < 8; j++) a[j] = fmaf(ex, (float)f[q][j], a[j]);
            }
        }
        // tail: 2 edges, predicated
        for (; e < deg; e += 2) {
            int ee = e + half;
            bool act = ee < deg;
            int es = act ? ee : (deg - 1);
            int u = adjr[es];
            float elvq = (H == 4) ? el[u * 4 + hd] : el[u];
            half8 f = *(const half8*)&feat[(size_t)u * HID + d0];
            float sc = elvq + er_h;
            sc = (sc > 0.f) ? sc : 0.2f * sc;
            float ex = act ? __expf(sc) : 0.f;
            sl += ex;
#pragma unroll
            for (int j = 0; j < 8; j++) a[j] = fmaf(ex, (float)f[j], a[j]);
        }

        // merge halves (each half holds partial msg + partial ex-sum)
#pragma unroll
        for (int j = 0; j < 8; j++) a[j] += __shfl_xor(a[j], 32);
        sl += __shfl_xor(sl, 32);
        float inv = 1.f / sl;

#pragma unroll
        for (int j = 0; j < 8; j++) {
            o[j] = fmaf(a[j], inv, bias[d0 + j]);
            if (RELU) o[j] = fmaxf(o[j], 0.f);
        }
    } else {
#pragma unroll
        for (int j = 0; j < 8; j++) {
            o[j] = bias[d0 + j];
            if (RELU) o[j] = fmaxf(o[j], 0.f);
        }
    }

    if (half == 0) {
        size_t base = (size_t)v * HID + d0;
        if (WF32) {
            *(float4*)&outf[base] = make_float4(o[0], o[1], o[2], o[3]);
            *(float4*)&outf[base + 4] = make_float4(o[4], o[5], o[6], o[7]);
        }
        if (WSPLIT) {
            bf16x8 hh, ll;
#pragma unroll
            for (int j = 0; j < 8; j++) {
                __bf16 hv = (__bf16)o[j];
                hh[j] = hv;
                ll[j] = (__bf16)(o[j] - (float)hv);
            }
            *(bf16x8*)&oh[base] = hh;
            *(bf16x8*)&ol[base] = ll;
        }
    }
}

// ---------------- launch ----------------

extern "C" void kernel_launch(void* const* d_in, const int* in_sizes, int n_in,
                              void* d_out, int out_size, void* d_ws, size_t ws_size,
                              hipStream_t stream) {
    const float* feats = (const float*)d_in[0];
    const int* src = (const int*)d_in[1];
    const int* dst = (const int*)d_in[2];
    const float* W0 = (const float*)d_in[3];
    const float* al0 = (const float*)d_in[4];
    const float* ar0 = (const float*)d_in[5];
    const float* b0 = (const float*)d_in[6];
    const float* W1 = (const float*)d_in[7];
    const float* al1 = (const float*)d_in[8];
    const float* ar1 = (const float*)d_in[9];
    const float* b1 = (const float*)d_in[10];
    const float* W2 = (const float*)d_in[11];
    const float* al2 = (const float*)d_in[12];
    const float* ar2 = (const float*)d_in[13];
    const float* b2 = (const float*)d_in[14];
    float* out = (float*)d_out;

    const int IN_DIM = 512;
    const int N = in_sizes[0] / IN_DIM;   // 50000
    const int E = in_sizes[1];            // 800000

    char* ws = (char*)d_ws;
    size_t off = 0;
    auto alloc = [&](size_t bytes) -> void* {
        void* p = ws + off;
        off = (off + bytes + 255) & ~(size_t)255;
        return p;
    };
    _Float16* featbuf = (_Float16*)alloc((size_t)N * HID * sizeof(_Float16));  // 25.6 MB
    float* el = (float*)alloc((size_t)N * 4 * sizeof(float));
    float* er = (float*)alloc((size_t)N * 4 * sizeof(float));
    int* cnt = (int*)alloc((size_t)N * sizeof(int));
    int* rowptr = (int*)alloc((size_t)(N + 1) * sizeof(int));
    int* cursor = (int*)alloc((size_t)N * sizeof(int));
    int* adj = (int*)alloc((size_t)E * sizeof(int));
    int nscanb = (N + 255) / 256;
    int* bsum = (int*)alloc((size_t)nscanb * sizeof(int));
    int* boff = (int*)alloc((size_t)nscanb * sizeof(int));
    __bf16* Ah = (__bf16*)alloc((size_t)N * HID * sizeof(__bf16));             // 25.6 MB
    __bf16* Al = (__bf16*)alloc((size_t)N * HID * sizeof(__bf16));             // 25.6 MB
    __bf16* Bht0 = (__bf16*)alloc((size_t)512 * HID * sizeof(__bf16));
    __bf16* Blt0 = (__bf16*)alloc((size_t)512 * HID * sizeof(__bf16));
    __bf16* Bht1 = (__bf16*)alloc((size_t)256 * HID * sizeof(__bf16));
    __bf16* Blt1 = (__bf16*)alloc((size_t)256 * HID * sizeof(__bf16));
    __bf16* Bht2 = (__bf16*)alloc((size_t)256 * HID * sizeof(__bf16));
    __bf16* Blt2 = (__bf16*)alloc((size_t)256 * HID * sizeof(__bf16));
    bool use_mfma = (off <= ws_size);

    // CSR build
    hipMemsetAsync(cnt, 0, (size_t)N * sizeof(int), stream);
    hist_kernel<<<(E + 255) / 256, 256, 0, stream>>>(dst, cnt, E);
    scan1_kernel<<<nscanb, 256, 0, stream>>>(cnt, bsum, N);
    scan2_kernel<<<1, 256, 0, stream>>>(bsum, boff, nscanb);
    scan3_kernel<<<nscanb, 256, 0, stream>>>(cnt, boff, rowptr, cursor, N);
    fill_kernel<<<(E + 255) / 256, 256, 0, stream>>>(src, dst, cursor, adj, E);

    dim3 ggrid(HID / 128, (N + 63) / 64);       // BM=64 tiles for MFMA path
    dim3 ggrid_fb(HID / 128, (N + 127) / 128);  // fallback keeps 128x128
    int aggb = (N + 3) / 4;

    if (use_mfma) {
        // all weights -> transposed bf16 hi/lo, one kernel
        splitT_all_kernel<<<(512 * 256 + 2 * 256 * 256) / 256, 256, 0, stream>>>(
            W0, W1, W2, Bht0, Blt0, Bht1, Blt1, Bht2, Blt2);

        // layer 0: 512 -> 4x64, relu (A split fused into staging; elr fused)
        gemm_mfma_kernel<true><<<ggrid, 256, 0, stream>>>(
            feats, nullptr, nullptr, Bht0, Blt0, featbuf, al0, ar0, el, er, N, 512, 4);
        agg_tpl<4, true, false, true><<<aggb, 256, 0, stream>>>(
            featbuf, el, er, rowptr, adj, b0, nullptr, Ah, Al, N);

        // layer 1: 256 -> 4x64, relu
        gemm_mfma_kernel<false><<<ggrid, 256, 0, stream>>>(
            nullptr, Ah, Al, Bht1, Blt1, featbuf, al1, ar1, el, er, N, 256, 4);
        agg_tpl<4, true, false, true><<<aggb, 256, 0, stream>>>(
            featbuf, el, er, rowptr, adj, b1, nullptr, Ah, Al, N);

        // layer 2: 256 -> 1x256, no act (elr via atomics -> zero first)
        hipMemsetAsync(el, 0, (size_t)N * 8 * sizeof(float), stream);  // el+er contiguous
        gemm_mfma_kernel<false><<<ggrid, 256, 0, stream>>>(
            nullptr, Ah, Al, Bht2, Blt2, featbuf, al2, ar2, el, er, N, 256, 1);
        agg_tpl<1, false, true, false><<<aggb, 256, 0, stream>>>(
            featbuf, el, er, rowptr, adj, b2, out, nullptr, nullptr, N);
    } else {
        gemm_kernel<<<ggrid_fb, 256, 0, stream>>>(feats, W0, featbuf, N, 512, HID);
        elr_kernel<<<N, 256, 0, stream>>>(featbuf, al0, ar0, el, er, 4);
        agg_tpl<4, true, true, false><<<aggb, 256, 0, stream>>>(
            featbuf, el, er, rowptr, adj, b0, out, nullptr, nullptr, N);

        gemm_kernel<<<ggrid_fb, 256, 0, stream>>>(out, W1, featbuf, N, 256, HID);
        elr_kernel<<<N, 256, 0, stream>>>(featbuf, al1, ar1, el, er, 4);
        agg_tpl<4, true, true, false><<<aggb, 256, 0, stream>>>(
            featbuf, el, er, rowptr, adj, b1, out, nullptr, nullptr, N);

        gemm_kernel<<<ggrid_fb, 256, 0, stream>>>(out, W2, featbuf, N, 256, HID);
        elr_kernel<<<N, 256, 0, stream>>>(featbuf, al2, ar2, el, er, 1);
        agg_tpl<1, false, true, false><<<aggb, 256, 0, stream>>>(
            featbuf, el, er, rowptr, adj, b2, out, nullptr, nullptr, N);
    }
}